// Round 7
// baseline (79342.780 us; speedup 1.0000x reference)
//
#include <hip/hip_runtime.h>
#include <hip/hip_cooperative_groups.h>
#include <cstddef>
#include <cstdint>

namespace cg = cooperative_groups;

// SentimentAnalysis: BiLSTM(H=512) -> LSTM(1024) -> attn pool -> fc -> lin
// B=64, T=512, E=300, H=512, C=2. All fp32.
//
// Round-6 (48.6 ms) post-mortem: ~1636 dependent launches; model says the
// step kernels' compute floor is 2-5 us, so ~30 ms is launch/serialization
// overhead and/or cross-launch L2 thrash. This round: persistent cooperative
// step kernels (one launch per 32-step / 16-step chunk, grid.sync between
// steps). Step math identical to round 6 (absmax 5.96e-8 verified).

#define T_SEQ 512
#define NB 64
#define TC1 32   // layer-1 chunk (x-projections, lstm1 steps)
#define TC2 16   // layer-2 sub-chunk (buf_s, lstm2 steps)

__device__ __forceinline__ float sigf(float x) {
    return 1.0f / (1.0f + expf(-x));
}

// ---------------- Tiled SGEMM: C[M,N] = (A@B) [+ C] [+ bias], opt relu -----
// BM=BN=128, BK=8, 256 threads, 8x8 per thread.
// Row remap (chunked): local row r -> global A-row (r>>tsh)*Trows + t0 + (r&tcm).
__global__ __launch_bounds__(256) void sgemm_bias(
    const float* __restrict__ A, const float* __restrict__ B,
    const float* __restrict__ bias, float* __restrict__ C,
    int M, int N, int K, int act, int accum,
    int chunked, int t0, int tsh, int tcm, int Trows)
{
    __shared__ float As[8][128];
    __shared__ float Bs[8][128];
    int tid = threadIdx.x;
    int row0 = blockIdx.y * 128, col0 = blockIdx.x * 128;
    int arow = tid >> 1, ak0 = (tid & 1) * 4;
    int bk = tid >> 5, bcol = (tid & 31) * 4;
    int ty = tid >> 4, tx = tid & 15;
    float acc[8][8] = {};
    int r = row0 + arow;
    int grow = chunked ? ((r >> tsh) * Trows + t0 + (r & tcm)) : r;
    const float* Aptr = A + (size_t)grow * K;
    bool arow_ok = r < M;

    for (int k0 = 0; k0 < K; k0 += 8) {
#pragma unroll
        for (int i = 0; i < 4; i++) {
            int k = k0 + ak0 + i;
            As[ak0 + i][arow] = (arow_ok && k < K) ? Aptr[k] : 0.0f;
        }
        {
            int k = k0 + bk;
            float4 v = make_float4(0.f, 0.f, 0.f, 0.f);
            if (k < K) v = *(const float4*)&B[(size_t)k * N + col0 + bcol];
            *(float4*)&Bs[bk][bcol] = v;
        }
        __syncthreads();
#pragma unroll
        for (int kk = 0; kk < 8; kk++) {
            float a[8], b[8];
#pragma unroll
            for (int i = 0; i < 8; i++) a[i] = As[kk][ty * 8 + i];
#pragma unroll
            for (int j = 0; j < 8; j++) b[j] = Bs[kk][tx * 8 + j];
#pragma unroll
            for (int i = 0; i < 8; i++)
#pragma unroll
                for (int j = 0; j < 8; j++)
                    acc[i][j] = fmaf(a[i], b[j], acc[i][j]);
        }
        __syncthreads();
    }

    float bj[8];
#pragma unroll
    for (int j = 0; j < 8; j++) bj[j] = accum ? 0.0f : bias[col0 + tx * 8 + j];
#pragma unroll
    for (int i = 0; i < 8; i++) {
        int rr = row0 + ty * 8 + i;
        if (rr >= M) continue;
        float* crow = &C[(size_t)rr * N + col0 + tx * 8];
#pragma unroll
        for (int j = 0; j < 8; j += 4) {
            float4 v;
            v.x = acc[i][j + 0] + bj[j + 0];
            v.y = acc[i][j + 1] + bj[j + 1];
            v.z = acc[i][j + 2] + bj[j + 2];
            v.w = acc[i][j + 3] + bj[j + 3];
            if (accum) {
                float4 o = *(const float4*)&crow[j];
                v.x += o.x; v.y += o.y; v.z += o.z; v.w += o.w;
            }
            if (act) {
                v.x = fmaxf(v.x, 0.f); v.y = fmaxf(v.y, 0.f);
                v.z = fmaxf(v.z, 0.f); v.w = fmaxf(v.w, 0.f);
            }
            *(float4*)&crow[j] = v;
        }
    }
}

// ---------------- LSTM layer 1: TC1 steps, one direction, cooperative ------
// grid 128 = ut(16) x bt(8); block 512 = kq(8) waves x 64 lanes.
// Lane: uq = lane&7 -> 4 units u0 = ut*32+uq*4; bq = lane>>3 -> b = bt*8+bq.
// Wave kq handles k in [kq*64, kq*64+64). LDS reduce, wave 0 does epilogue.
// grid.sync() per step replaces the per-step kernel launch (round 6).
__global__ __launch_bounds__(512) void lstm1_coop(
    const float* __restrict__ Gx, const float* __restrict__ Wh,
    float* __restrict__ hf_chunk, float* __restrict__ hf_roll,
    float* __restrict__ hb, float* __restrict__ cbuf_g,
    int t_base, int dir)
{
    cg::grid_group grid = cg::this_grid();
    __shared__ float red[7][16][64];
    int bx = blockIdx.x;
    int ut = bx & 15;
    int bt = bx >> 4;
    int tid = threadIdx.x;
    int kq = tid >> 6;
    int lane = tid & 63;
    int uq = lane & 7, bq = lane >> 3;
    int u0 = ut * 32 + uq * 4;
    int b = bt * 8 + bq;

    for (int j = 0; j < TC1; j++) {
        int t = t_base + j;
        int t_eff = dir ? (T_SEQ - 1 - t) : t;
        int tl = dir ? (TC1 - 1 - j) : j;

        float acc[16];
#pragma unroll
        for (int i = 0; i < 16; i++) acc[i] = 0.0f;

        if (t > 0) {
            const float* hp = dir
                ? hb + ((size_t)b * T_SEQ + t_eff + 1) * 512
                : hf_roll + ((t - 1) & 1) * (NB * 512) + b * 512;
            int k0 = kq * 64;
            for (int k = k0; k < k0 + 64; k += 4) {
                float4 h4 = *(const float4*)&hp[k];
                float hv[4] = { h4.x, h4.y, h4.z, h4.w };
#pragma unroll
                for (int kk = 0; kk < 4; kk++) {
                    const float* wr = Wh + (size_t)(k + kk) * 2048;
#pragma unroll
                    for (int g = 0; g < 4; g++) {
                        float4 w4 = *(const float4*)&wr[g * 512 + u0];
                        acc[g * 4 + 0] = fmaf(hv[kk], w4.x, acc[g * 4 + 0]);
                        acc[g * 4 + 1] = fmaf(hv[kk], w4.y, acc[g * 4 + 1]);
                        acc[g * 4 + 2] = fmaf(hv[kk], w4.z, acc[g * 4 + 2]);
                        acc[g * 4 + 3] = fmaf(hv[kk], w4.w, acc[g * 4 + 3]);
                    }
                }
            }
        }

        if (kq > 0) {
#pragma unroll
            for (int i = 0; i < 16; i++) red[kq - 1][i][lane] = acc[i];
        }
        __syncthreads();

        if (kq == 0) {
#pragma unroll
            for (int q = 0; q < 7; q++)
#pragma unroll
                for (int i = 0; i < 16; i++) acc[i] += red[q][i][lane];

            size_t gx = ((size_t)b * TC1 + tl) * 2048;
            float4 xi = *(const float4*)&Gx[gx + u0];
            float4 xf = *(const float4*)&Gx[gx + 512 + u0];
            float4 xg = *(const float4*)&Gx[gx + 1024 + u0];
            float4 xo = *(const float4*)&Gx[gx + 1536 + u0];
            float* cbuf = cbuf_g + b * 512 + u0;
            float4 cp = (t > 0) ? *(const float4*)cbuf
                                : make_float4(0.f, 0.f, 0.f, 0.f);
            float xiv[4] = { xi.x, xi.y, xi.z, xi.w };
            float xfv[4] = { xf.x, xf.y, xf.z, xf.w };
            float xgv[4] = { xg.x, xg.y, xg.z, xg.w };
            float xov[4] = { xo.x, xo.y, xo.z, xo.w };
            float cpv[4] = { cp.x, cp.y, cp.z, cp.w };
            float cn[4], hn[4];
#pragma unroll
            for (int i = 0; i < 4; i++) {
                float iv = sigf(acc[0 + i] + xiv[i]);
                float fv = sigf(acc[4 + i] + xfv[i]);
                float gv = tanhf(acc[8 + i] + xgv[i]);
                float ov = sigf(acc[12 + i] + xov[i]);
                float c = fv * cpv[i] + iv * gv;
                cn[i] = c;
                hn[i] = ov * tanhf(c);
            }
            *(float4*)cbuf = make_float4(cn[0], cn[1], cn[2], cn[3]);
            float4 h4 = make_float4(hn[0], hn[1], hn[2], hn[3]);
            if (dir) {
                *(float4*)&hb[((size_t)b * T_SEQ + t_eff) * 512 + u0] = h4;
            } else {
                *(float4*)&hf_roll[(t & 1) * (NB * 512) + b * 512 + u0] = h4;
                *(float4*)&hf_chunk[((size_t)b * TC1 + tl) * 512 + u0] = h4;
            }
        }
        grid.sync();
    }
}

// ---------------- LSTM layer 2: TC2 steps, cooperative, fused score/ctx ----
// grid 256 = ut(32) x bt(8); block 512 = kq(8) x 64 lanes.
// Lane: uq = lane&7 -> u0 = ut*32+uq*4; bq = lane>>3 -> b = bt*8+bq.
// Wave kq: k in [kq*128, kq*128+128).
__global__ __launch_bounds__(512) void lstm2_coop(
    const float* __restrict__ buf_s, const float* __restrict__ Wh_s,
    float* __restrict__ hroll, float* __restrict__ c_s,
    float* __restrict__ scores, float* __restrict__ ctx_num,
    const float* __restrict__ attn_w, int t_base)
{
    cg::grid_group grid = cg::this_grid();
    __shared__ float red[7][16][64];
    int bx = blockIdx.x;
    int ut = bx & 31;
    int bt = bx >> 5;
    int tid = threadIdx.x;
    int kq = tid >> 6;
    int lane = tid & 63;
    int uq = lane & 7, bq = lane >> 3;
    int u0 = ut * 32 + uq * 4;
    int b = bt * 8 + bq;

    for (int j = 0; j < TC2; j++) {
        int t = t_base + j;
        int tl = j;

        const float* hp = hroll + ((t - 1) & 1) * (NB * 1024) + b * 1024;

        float acc[16];
#pragma unroll
        for (int i = 0; i < 16; i++) acc[i] = 0.0f;

        if (t > 0) {
            int k0 = kq * 128;
            for (int k = k0; k < k0 + 128; k += 4) {
                float4 h4 = *(const float4*)&hp[k];
                float hv[4] = { h4.x, h4.y, h4.z, h4.w };
#pragma unroll
                for (int kk = 0; kk < 4; kk++) {
                    const float* wr = Wh_s + (size_t)(k + kk) * 4096;
#pragma unroll
                    for (int g = 0; g < 4; g++) {
                        float4 w4 = *(const float4*)&wr[g * 1024 + u0];
                        acc[g * 4 + 0] = fmaf(hv[kk], w4.x, acc[g * 4 + 0]);
                        acc[g * 4 + 1] = fmaf(hv[kk], w4.y, acc[g * 4 + 1]);
                        acc[g * 4 + 2] = fmaf(hv[kk], w4.z, acc[g * 4 + 2]);
                        acc[g * 4 + 3] = fmaf(hv[kk], w4.w, acc[g * 4 + 3]);
                    }
                }
            }
        }

        if (kq > 0) {
#pragma unroll
            for (int i = 0; i < 16; i++) red[kq - 1][i][lane] = acc[i];
        }
        __syncthreads();

        if (kq == 0) {
#pragma unroll
            for (int q = 0; q < 7; q++)
#pragma unroll
                for (int i = 0; i < 16; i++) acc[i] += red[q][i][lane];

            size_t gx = ((size_t)b * TC2 + tl) * 4096;
            float4 xi = *(const float4*)&buf_s[gx + u0];
            float4 xf = *(const float4*)&buf_s[gx + 1024 + u0];
            float4 xg = *(const float4*)&buf_s[gx + 2048 + u0];
            float4 xo = *(const float4*)&buf_s[gx + 3072 + u0];
            float* cbuf = c_s + b * 1024 + u0;
            float4 cp = (t > 0) ? *(const float4*)cbuf
                                : make_float4(0.f, 0.f, 0.f, 0.f);
            float xiv[4] = { xi.x, xi.y, xi.z, xi.w };
            float xfv[4] = { xf.x, xf.y, xf.z, xf.w };
            float xgv[4] = { xg.x, xg.y, xg.z, xg.w };
            float xov[4] = { xo.x, xo.y, xo.z, xo.w };
            float cpv[4] = { cp.x, cp.y, cp.z, cp.w };
            float cn[4], hn[4];
#pragma unroll
            for (int i = 0; i < 4; i++) {
                float iv = sigf(acc[0 + i] + xiv[i]);
                float fv = sigf(acc[4 + i] + xfv[i]);
                float gv = tanhf(acc[8 + i] + xgv[i]);
                float ov = sigf(acc[12 + i] + xov[i]);
                float c = fv * cpv[i] + iv * gv;
                cn[i] = c;
                hn[i] = ov * tanhf(c);
            }
            *(float4*)cbuf = make_float4(cn[0], cn[1], cn[2], cn[3]);
            *(float4*)&hroll[(t & 1) * (NB * 1024) + b * 1024 + u0] =
                make_float4(hn[0], hn[1], hn[2], hn[3]);

            // fused attention score partial: 4 units/thread, 8-lane uq group
            // reduce -> 1 atomic per (block, b): 32 adds/address.
            float4 aw = *(const float4*)&attn_w[u0];
            float sc = tanhf(hn[0]) * aw.x + tanhf(hn[1]) * aw.y +
                       tanhf(hn[2]) * aw.z + tanhf(hn[3]) * aw.w;
            sc += __shfl_down(sc, 4);
            sc += __shfl_down(sc, 2);
            sc += __shfl_down(sc, 1);
            if (uq == 0) atomicAdd(&scores[b * T_SEQ + t], sc);

            // fused ctx accumulation for step t-1 (scores[t-1] complete
            // before the previous grid.sync / launch boundary)
            if (t > 0) {
                float e = expf(scores[b * T_SEQ + (t - 1)]);
                float4 hp4 = *(const float4*)&hp[u0];
                float4 cx = *(const float4*)&ctx_num[b * 1024 + u0];
                cx.x = fmaf(e, hp4.x, cx.x);
                cx.y = fmaf(e, hp4.y, cx.y);
                cx.z = fmaf(e, hp4.z, cx.z);
                cx.w = fmaf(e, hp4.w, cx.w);
                *(float4*)&ctx_num[b * 1024 + u0] = cx;
            }
        }
        grid.sync();
    }
}

// ---------------- zero-init for scores+ctx_num -----------------------------
__global__ __launch_bounds__(256) void zero_kernel(float* __restrict__ p, int n)
{
    int i = blockIdx.x * 256 + threadIdx.x;
    if (i < n) p[i] = 0.0f;
}

// ---------------- attention finalize ---------------------------------------
__global__ __launch_bounds__(256) void attn_final(
    const float* __restrict__ scores, const float* __restrict__ ctx_num,
    const float* __restrict__ hroll, float* __restrict__ out_alpha,
    float* __restrict__ ctx)
{
    __shared__ float red[256];
    int b = blockIdx.x, tid = threadIdx.x;
    float v0 = scores[b * T_SEQ + tid];
    float v1 = scores[b * T_SEQ + tid + 256];
    red[tid] = fmaxf(v0, v1);
    __syncthreads();
    for (int s = 128; s > 0; s >>= 1) {
        if (tid < s) red[tid] = fmaxf(red[tid], red[tid + s]);
        __syncthreads();
    }
    float mx = red[0];
    __syncthreads();
    float e0 = expf(v0 - mx), e1 = expf(v1 - mx);
    red[tid] = e0 + e1;
    __syncthreads();
    for (int s = 128; s > 0; s >>= 1) {
        if (tid < s) red[tid] += red[tid + s];
        __syncthreads();
    }
    float d2 = red[0];
    float inv = 1.0f / d2;
    out_alpha[b * T_SEQ + tid] = e0 * inv;
    out_alpha[b * T_SEQ + tid + 256] = e1 * inv;

    float d = d2 * expf(mx);
    float es511 = expf(scores[b * T_SEQ + 511]);
    const float* h511 = hroll + 1 * (NB * 1024) + b * 1024;  // 511&1 == 1
    float invd = 1.0f / d;
    float4 cn = *(const float4*)&ctx_num[b * 1024 + tid * 4];
    float4 hv = *(const float4*)&h511[tid * 4];
    float4 o;
    o.x = (cn.x + es511 * hv.x) * invd;
    o.y = (cn.y + es511 * hv.y) * invd;
    o.z = (cn.z + es511 * hv.z) * invd;
    o.w = (cn.w + es511 * hv.w) * invd;
    *(float4*)&ctx[b * 1024 + tid * 4] = o;
}

// ---------------- final linear: out[b,0:2] ---------------------------------
__global__ __launch_bounds__(64) void lin_kernel(
    const float* __restrict__ fcout, const float* __restrict__ lin_W,
    const float* __restrict__ lin_b, float* __restrict__ out)
{
    int b = blockIdx.x, lane = threadIdx.x;
    float p0 = 0.f, p1 = 0.f;
    for (int k = lane; k < 1024; k += 64) {
        float h = fcout[b * 1024 + k];
        p0 = fmaf(h, lin_W[k * 2 + 0], p0);
        p1 = fmaf(h, lin_W[k * 2 + 1], p1);
    }
#pragma unroll
    for (int off = 32; off > 0; off >>= 1) {
        p0 += __shfl_down(p0, off);
        p1 += __shfl_down(p1, off);
    }
    if (lane == 0) {
        out[b * 2 + 0] = p0 + lin_b[0];
        out[b * 2 + 1] = p1 + lin_b[1];
    }
}

__global__ void sentinel_kernel(float* out) { out[0] = 1.0e6f; }

extern "C" void kernel_launch(void* const* d_in, const int* in_sizes, int n_in,
                              void* d_out, int out_size, void* d_ws, size_t ws_size,
                              hipStream_t stream) {
    const float* x      = (const float*)d_in[0];
    const float* Wx_f   = (const float*)d_in[1];
    const float* Wh_f   = (const float*)d_in[2];
    const float* b_f    = (const float*)d_in[3];
    const float* Wx_b   = (const float*)d_in[4];
    const float* Wh_b   = (const float*)d_in[5];
    const float* b_b    = (const float*)d_in[6];
    const float* Wx_s   = (const float*)d_in[7];
    const float* Wh_s   = (const float*)d_in[8];
    const float* b_s    = (const float*)d_in[9];
    const float* attn_w = (const float*)d_in[10];
    const float* fc_W   = (const float*)d_in[11];
    const float* fc_b   = (const float*)d_in[12];
    const float* lin_W  = (const float*)d_in[13];
    const float* lin_b  = (const float*)d_in[14];
    float* out = (float*)d_out;

    float* w = (float*)d_ws;
    float* hb       = w; w += (size_t)NB * T_SEQ * 512;    // 64 MiB
    float* hf_chunk = w; w += (size_t)NB * TC1 * 512;      // 4 MiB
    float* buf_b = w;                                      // 16 MiB aliased
    float* buf_f = w;
    float* buf_s = w;
    w += (size_t)NB * TC1 * 2048;
    float* hf_roll = w; w += 2 * NB * 512;
    float* hroll   = w; w += 2 * NB * 1024;
    float* c_f     = w; w += NB * 512;
    float* c_b     = w; w += NB * 512;
    float* c_s     = w; w += NB * 1024;
    float* scores  = w; w += NB * T_SEQ;
    float* ctx_num = w; w += NB * 1024;
    float* ctx     = w; w += NB * 1024;
    float* fcout   = w; w += NB * 1024;

    size_t need_bytes = (size_t)((char*)w - (char*)d_ws);
    if (ws_size < need_bytes) {
        sentinel_kernel<<<1, 1, 0, stream>>>(out);
        return;
    }

    const int NCH1 = T_SEQ / TC1;  // 16

    {
        int n = NB * T_SEQ + NB * 1024;  // scores + ctx_num (contiguous)
        zero_kernel<<<(n + 255) / 256, 256, 0, stream>>>(scores, n);
    }

    // Phase 1: backward-only scan (chunk GEMM + one cooperative 32-step kernel)
    for (int i = 0; i < NCH1; i++) {
        int t0b = T_SEQ - (i + 1) * TC1;
        sgemm_bias<<<dim3(2048 / 128, (NB * TC1) / 128), 256, 0, stream>>>(
            x, Wx_b, b_b, buf_b, NB * TC1, 2048, 300, 0, 0,
            1, t0b, 5, TC1 - 1, T_SEQ);
        {
            int tb = i * TC1, dirv = 1;
            void* args[] = { (void*)&buf_b, (void*)&Wh_b, (void*)&hf_chunk,
                             (void*)&hf_roll, (void*)&hb, (void*)&c_b,
                             (void*)&tb, (void*)&dirv };
            hipLaunchCooperativeKernel((void*)lstm1_coop, dim3(128), dim3(512),
                                       args, 0, stream);
        }
    }

    // Phase 2: forward scan interleaved with layer-2
    for (int i = 0; i < NCH1; i++) {
        int t0 = i * TC1;
        sgemm_bias<<<dim3(2048 / 128, (NB * TC1) / 128), 256, 0, stream>>>(
            x, Wx_f, b_f, buf_f, NB * TC1, 2048, 300, 0, 0,
            1, t0, 5, TC1 - 1, T_SEQ);
        {
            int tb = t0, dirv = 0;
            void* args[] = { (void*)&buf_f, (void*)&Wh_f, (void*)&hf_chunk,
                             (void*)&hf_roll, (void*)&hb, (void*)&c_f,
                             (void*)&tb, (void*)&dirv };
            hipLaunchCooperativeKernel((void*)lstm1_coop, dim3(128), dim3(512),
                                       args, 0, stream);
        }
        for (int h = 0; h < 2; h++) {
            int st0 = h * TC2;
            sgemm_bias<<<dim3(4096 / 128, (NB * TC2) / 128), 256, 0, stream>>>(
                hf_chunk, Wx_s, b_s, buf_s, NB * TC2, 4096, 512, 0, 0,
                1, st0, 4, TC2 - 1, TC1);
            sgemm_bias<<<dim3(4096 / 128, (NB * TC2) / 128), 256, 0, stream>>>(
                hb, Wx_s + (size_t)512 * 4096, b_s, buf_s,
                NB * TC2, 4096, 512, 0, 1,
                1, t0 + st0, 4, TC2 - 1, T_SEQ);
            {
                int tb = t0 + st0;
                void* args[] = { (void*)&buf_s, (void*)&Wh_s, (void*)&hroll,
                                 (void*)&c_s, (void*)&scores, (void*)&ctx_num,
                                 (void*)&attn_w, (void*)&tb };
                hipLaunchCooperativeKernel((void*)lstm2_coop, dim3(256),
                                           dim3(512), args, 0, stream);
            }
        }
    }

    attn_final<<<NB, 256, 0, stream>>>(scores, ctx_num, hroll, out + 128, ctx);
    sgemm_bias<<<dim3(1024 / 128, 1), 256, 0, stream>>>(
        ctx, fc_W, fc_b, fcout, 64, 1024, 1024, 1, 0, 0, 0, 0, 0, 0);
    lin_kernel<<<NB, 64, 0, stream>>>(fcout, lin_W, lin_b, out);
}